// Round 9
// baseline (50.272 us; speedup 1.0000x reference)
//
#include <hip/hip_runtime.h>

// Problem constants (from reference setup_inputs): h_all [T,B,D] fp32
#define T_DIM 2048
#define B_DIM 64
#define D_DIM 512
#define CHUNKS 16                         // t-chunks per batch
#define ROWS_PER_BLOCK (T_DIM / CHUNKS)   // 128 rows of h per block
#define NWAVES 8                          // 512 threads
#define ROWS_PER_WAVE (ROWS_PER_BLOCK / NWAVES)  // 16
#define RSQRT_D 0.044194173824159216f     // 1/sqrt(512)

typedef float f32x4 __attribute__((ext_vector_type(4)));

// ws layout (floats): Ppart[B][CHUNKS][D] | Spart[B][CHUNKS]

// Pass 1: identical to Round 8 except the two h-row loads are NONTEMPORAL
// (isolated single-variable test; R6 bundled nt with the unroll-8 VGPR-cliff
// regression so nt was never measured alone). h_all is a 268MB read-once
// stream 8x the aggregate L2 -- nt avoids polluting L2/L3 so partials stay
// hot for pass 2. unroll stays 4 (64-VGPR occupancy cliff; R6/R8 lesson).
// Plain stores, no atomics, no fences (R3 lesson).
__global__ __launch_bounds__(512)
void ap_partial_kernel(const float* __restrict__ h,
                       float* __restrict__ Ppart,   // [B][CHUNKS][D]
                       float* __restrict__ Spart)   // [B][CHUNKS]
{
    const int b     = blockIdx.x % B_DIM;
    const int chunk = blockIdx.x / B_DIM;
    const int tid   = threadIdx.x;
    const int wave  = tid >> 6;
    const int lane  = tid & 63;

    const size_t rowStride = (size_t)B_DIM * D_DIM;   // floats between t's

    const int d0 = lane * 4;
    const int d1 = D_DIM / 2 + lane * 4;   // 256 + 4*lane

    const float* hl = h + (size_t)(T_DIM - 1) * rowStride + (size_t)b * D_DIM;
    const f32x4 hl0 = *(const f32x4*)(hl + d0);
    const f32x4 hl1 = *(const f32x4*)(hl + d1);

    float acc0 = 0.f, acc1 = 0.f, acc2 = 0.f, acc3 = 0.f;
    float acc4 = 0.f, acc5 = 0.f, acc6 = 0.f, acc7 = 0.f;
    float s = 0.f;

    const int t0 = chunk * ROWS_PER_BLOCK + wave * ROWS_PER_WAVE;
    const float* base = h + (size_t)t0 * rowStride + (size_t)b * D_DIM;

    #pragma unroll 4
    for (int i = 0; i < ROWS_PER_WAVE; ++i) {
        const float* row = base + (size_t)i * rowStride;
        // read-once stream: nontemporal dwordx4 (contiguous 1 KB across wave)
        const f32x4 v0 = __builtin_nontemporal_load((const f32x4*)(row + d0));
        const f32x4 v1 = __builtin_nontemporal_load((const f32x4*)(row + d1));

        // per-lane partial dot over its 8 elements
        float dp;
        dp = v0.x * hl0.x;
        dp = fmaf(v0.y, hl0.y, dp);
        dp = fmaf(v0.z, hl0.z, dp);
        dp = fmaf(v0.w, hl0.w, dp);
        dp = fmaf(v1.x, hl1.x, dp);
        dp = fmaf(v1.y, hl1.y, dp);
        dp = fmaf(v1.z, hl1.z, dp);
        dp = fmaf(v1.w, hl1.w, dp);

        // 64-lane butterfly reduce (wave = 64 on CDNA)
        #pragma unroll
        for (int m = 1; m < 64; m <<= 1)
            dp += __shfl_xor(dp, m, 64);

        const float r = fmaxf(dp * RSQRT_D, 0.f);

        acc0 = fmaf(r, v0.x, acc0);
        acc1 = fmaf(r, v0.y, acc1);
        acc2 = fmaf(r, v0.z, acc2);
        acc3 = fmaf(r, v0.w, acc3);
        acc4 = fmaf(r, v1.x, acc4);
        acc5 = fmaf(r, v1.y, acc5);
        acc6 = fmaf(r, v1.z, acc6);
        acc7 = fmaf(r, v1.w, acc7);
        s += r;   // r is wave-uniform after reduce
    }

    // Cross-wave reduce in LDS, then plain stores of this block's partial.
    __shared__ float accs[NWAVES][D_DIM];   // 16 KiB
    __shared__ float ssum[NWAVES];

    *(f32x4*)&accs[wave][d0] = (f32x4){acc0, acc1, acc2, acc3};
    *(f32x4*)&accs[wave][d1] = (f32x4){acc4, acc5, acc6, acc7};
    if (lane == 0) ssum[wave] = s;
    __syncthreads();

    // 512 threads: thread tid owns element d = tid.
    const size_t pbase = ((size_t)b * CHUNKS + chunk) * D_DIM;
    float v = 0.f;
    #pragma unroll
    for (int w = 0; w < NWAVES; ++w)
        v += accs[w][tid];
    Ppart[pbase + tid] = v;

    if (tid == 0) {
        float sv = 0.f;
        #pragma unroll
        for (int w = 0; w < NWAVES; ++w)
            sv += ssum[w];
        Spart[b * CHUNKS + chunk] = sv;
    }
}

// Pass 2: out[b,d] = sum_c P[b][c][d] / (sum_c S[b][c] + 1e-9)
// 64 blocks x 128 threads; thread t owns d=4t (float4). Per-b reads are one
// contiguous 32 KiB stream, L3-hot. Fixed order -> deterministic.
__global__ __launch_bounds__(128)
void ap_reduce_kernel(const float* __restrict__ Ppart,
                      const float* __restrict__ Spart,
                      float* __restrict__ out)
{
    const int b = blockIdx.x;
    const int t = threadIdx.x;

    float s = 0.f;
    #pragma unroll
    for (int c = 0; c < CHUNKS; ++c)
        s += Spart[b * CHUNKS + c];
    const float inv = 1.0f / (s + 1e-9f);

    const f32x4* P = (const f32x4*)(Ppart + (size_t)b * CHUNKS * D_DIM);
    const int nd4 = D_DIM / 4;   // 128 float4 per chunk row

    f32x4 acc = (f32x4){0.f, 0.f, 0.f, 0.f};
    #pragma unroll
    for (int c = 0; c < CHUNKS; ++c) {
        acc += P[c * nd4 + t];
    }
    acc *= inv;
    ((f32x4*)(out + (size_t)b * D_DIM))[t] = acc;
}

extern "C" void kernel_launch(void* const* d_in, const int* in_sizes, int n_in,
                              void* d_out, int out_size, void* d_ws, size_t ws_size,
                              hipStream_t stream)
{
    const float* h = (const float*)d_in[0];   // h_all [T,B,D] fp32; xin (d_in[1]) unused
    float* ws    = (float*)d_ws;
    float* Ppart = ws;                                      // [B][CHUNKS][D]
    float* Spart = ws + (size_t)B_DIM * CHUNKS * D_DIM;     // [B][CHUNKS]

    ap_partial_kernel<<<B_DIM * CHUNKS, 512, 0, stream>>>(h, Ppart, Spart);
    ap_reduce_kernel<<<B_DIM, 128, 0, stream>>>(Ppart, Spart, (float*)d_out);
}

// Round 10
// 48.359 us; speedup vs baseline: 1.0396x; 1.0396x over previous
//
#include <hip/hip_runtime.h>

// Problem constants (from reference setup_inputs): h_all [T,B,D] fp32
#define T_DIM 2048
#define B_DIM 64
#define D_DIM 512
#define CHUNKS 16                         // t-chunks per batch
#define ROWS_PER_BLOCK (T_DIM / CHUNKS)   // 128 rows of h per block
#define NWAVES 8                          // 512 threads
#define ROWS_PER_WAVE (ROWS_PER_BLOCK / NWAVES)  // 16
#define RSQRT_D 0.044194173824159216f     // 1/sqrt(512)

typedef float f32x4 __attribute__((ext_vector_type(4)));

// ws layout (floats): Ppart[B][CHUNKS][D] | Spart[B][CHUNKS]
// CHUNKS=16: partials 4.2 MB RW; grid 1024 blocks x 8 waves = full occupancy.

// FINAL (Round-8 state, best measured 48.5 us ~= 89% of achievable-BW bound):
// - one-pass streaming: each h row read exactly once (268 MB floor = 42.6 us)
// - dense per-instruction coalescing: lane i owns byte 16i / 1024+16i of the
//   row -> each global_load_dwordx4 covers a contiguous 1 KB across the wave
// - unroll 4: in-flight load data 32 VGPR, total 44 -> full 32 waves/CU
//   (unroll 8 breaches the 64-VGPR occupancy cliff: R6 regression)
// - plain loads: nontemporal policy isolated-tested in R9, -3.6% (confirmed
//   harmful for this streaming pattern on gfx950)
// - plain stores + tiny second dispatch: device-scope fence fusion tested in
//   R3, +150 us (2048 blocks x __threadfence serializes L2 writeback-drains)
__global__ __launch_bounds__(512)
void ap_partial_kernel(const float* __restrict__ h,
                       float* __restrict__ Ppart,   // [B][CHUNKS][D]
                       float* __restrict__ Spart)   // [B][CHUNKS]
{
    const int b     = blockIdx.x % B_DIM;
    const int chunk = blockIdx.x / B_DIM;
    const int tid   = threadIdx.x;
    const int wave  = tid >> 6;
    const int lane  = tid & 63;

    const size_t rowStride = (size_t)B_DIM * D_DIM;   // floats between t's

    const int d0 = lane * 4;
    const int d1 = D_DIM / 2 + lane * 4;   // 256 + 4*lane

    const float* hl = h + (size_t)(T_DIM - 1) * rowStride + (size_t)b * D_DIM;
    const f32x4 hl0 = *(const f32x4*)(hl + d0);
    const f32x4 hl1 = *(const f32x4*)(hl + d1);

    float acc0 = 0.f, acc1 = 0.f, acc2 = 0.f, acc3 = 0.f;
    float acc4 = 0.f, acc5 = 0.f, acc6 = 0.f, acc7 = 0.f;
    float s = 0.f;

    const int t0 = chunk * ROWS_PER_BLOCK + wave * ROWS_PER_WAVE;
    const float* base = h + (size_t)t0 * rowStride + (size_t)b * D_DIM;

    #pragma unroll 4
    for (int i = 0; i < ROWS_PER_WAVE; ++i) {
        const float* row = base + (size_t)i * rowStride;
        const f32x4 v0 = *(const f32x4*)(row + d0);   // contiguous 1 KB across wave
        const f32x4 v1 = *(const f32x4*)(row + d1);   // contiguous 1 KB across wave

        // per-lane partial dot over its 8 elements
        float dp;
        dp = v0.x * hl0.x;
        dp = fmaf(v0.y, hl0.y, dp);
        dp = fmaf(v0.z, hl0.z, dp);
        dp = fmaf(v0.w, hl0.w, dp);
        dp = fmaf(v1.x, hl1.x, dp);
        dp = fmaf(v1.y, hl1.y, dp);
        dp = fmaf(v1.z, hl1.z, dp);
        dp = fmaf(v1.w, hl1.w, dp);

        // 64-lane butterfly reduce (wave = 64 on CDNA)
        #pragma unroll
        for (int m = 1; m < 64; m <<= 1)
            dp += __shfl_xor(dp, m, 64);

        const float r = fmaxf(dp * RSQRT_D, 0.f);

        acc0 = fmaf(r, v0.x, acc0);
        acc1 = fmaf(r, v0.y, acc1);
        acc2 = fmaf(r, v0.z, acc2);
        acc3 = fmaf(r, v0.w, acc3);
        acc4 = fmaf(r, v1.x, acc4);
        acc5 = fmaf(r, v1.y, acc5);
        acc6 = fmaf(r, v1.z, acc6);
        acc7 = fmaf(r, v1.w, acc7);
        s += r;   // r is wave-uniform after reduce
    }

    // Cross-wave reduce in LDS, then plain stores of this block's partial.
    __shared__ float accs[NWAVES][D_DIM];   // 16 KiB
    __shared__ float ssum[NWAVES];

    *(f32x4*)&accs[wave][d0] = (f32x4){acc0, acc1, acc2, acc3};
    *(f32x4*)&accs[wave][d1] = (f32x4){acc4, acc5, acc6, acc7};
    if (lane == 0) ssum[wave] = s;
    __syncthreads();

    // 512 threads: thread tid owns element d = tid.
    const size_t pbase = ((size_t)b * CHUNKS + chunk) * D_DIM;
    float v = 0.f;
    #pragma unroll
    for (int w = 0; w < NWAVES; ++w)
        v += accs[w][tid];
    Ppart[pbase + tid] = v;

    if (tid == 0) {
        float sv = 0.f;
        #pragma unroll
        for (int w = 0; w < NWAVES; ++w)
            sv += ssum[w];
        Spart[b * CHUNKS + chunk] = sv;
    }
}

// Pass 2: out[b,d] = sum_c P[b][c][d] / (sum_c S[b][c] + 1e-9)
// 64 blocks x 128 threads; thread t owns d=4t (float4). Per-b reads are one
// contiguous 32 KiB stream, L2/L3-hot. Fixed order -> deterministic.
__global__ __launch_bounds__(128)
void ap_reduce_kernel(const float* __restrict__ Ppart,
                      const float* __restrict__ Spart,
                      float* __restrict__ out)
{
    const int b = blockIdx.x;
    const int t = threadIdx.x;

    float s = 0.f;
    #pragma unroll
    for (int c = 0; c < CHUNKS; ++c)
        s += Spart[b * CHUNKS + c];
    const float inv = 1.0f / (s + 1e-9f);

    const f32x4* P = (const f32x4*)(Ppart + (size_t)b * CHUNKS * D_DIM);
    const int nd4 = D_DIM / 4;   // 128 float4 per chunk row

    f32x4 acc = (f32x4){0.f, 0.f, 0.f, 0.f};
    #pragma unroll
    for (int c = 0; c < CHUNKS; ++c) {
        acc += P[c * nd4 + t];
    }
    acc *= inv;
    ((f32x4*)(out + (size_t)b * D_DIM))[t] = acc;
}

extern "C" void kernel_launch(void* const* d_in, const int* in_sizes, int n_in,
                              void* d_out, int out_size, void* d_ws, size_t ws_size,
                              hipStream_t stream)
{
    const float* h = (const float*)d_in[0];   // h_all [T,B,D] fp32; xin (d_in[1]) unused
    float* ws    = (float*)d_ws;
    float* Ppart = ws;                                      // [B][CHUNKS][D]
    float* Spart = ws + (size_t)B_DIM * CHUNKS * D_DIM;     // [B][CHUNKS]

    ap_partial_kernel<<<B_DIM * CHUNKS, 512, 0, stream>>>(h, Ppart, Spart);
    ap_reduce_kernel<<<B_DIM, 128, 0, stream>>>(Ppart, Spart, (float*)d_out);
}